// Round 7
// baseline (408.213 us; speedup 1.0000x reference)
//
#include <hip/hip_runtime.h>
#include <stdint.h>

typedef short short8 __attribute__((ext_vector_type(8)));
typedef float floatx4 __attribute__((ext_vector_type(4)));
typedef float floatx16 __attribute__((ext_vector_type(16)));
typedef unsigned uint4v __attribute__((ext_vector_type(4)));

#define MFMA16(a, b, c) __builtin_amdgcn_mfma_f32_16x16x32_bf16((a), (b), (c), 0, 0, 0)
#define MFMA32(a, b, c) __builtin_amdgcn_mfma_f32_32x32x16_bf16((a), (b), (c), 0, 0, 0)

#define SPLITS 4
// staged chunk image: K 64x136 shorts (17408 B) | V 160x72 shorts (23040 B) | pad 512 B
#define CHUNK_BYTES 40960
#define CHUNK_SHORTS 20480
#define VOFF_SHORTS 8704

typedef __attribute__((address_space(1))) const void* gas1_cp;
typedef __attribute__((address_space(3))) void* las3_p;

__device__ __forceinline__ void gload_lds16(const void* g, void* l) {
    __builtin_amdgcn_global_load_lds((gas1_cp)g, (las3_p)l, 16, 0, 0);
}

__device__ __forceinline__ unsigned short f2bf(float f) {
    union { float f; unsigned u; } v; v.f = f;
    unsigned u = v.u;
    unsigned r = (u + 0x7FFFu + ((u >> 16) & 1u)) >> 16;
    return (unsigned short)r;
}
// round-half-up single float -> bf16 (bit-identical to pkfast halves)
__device__ __forceinline__ unsigned short us(float f) {
    return (unsigned short)((__float_as_uint(f) + 0x8000u) >> 16);
}
// fast pack: round-half-up both floats to bf16, pack lo|hi<<16 in one v_perm
__device__ __forceinline__ unsigned pkfast(float lo, float hi) {
    unsigned a = __float_as_uint(lo) + 0x8000u;
    unsigned b = __float_as_uint(hi) + 0x8000u;
    return __builtin_amdgcn_perm(b, a, 0x07060302u);
}

// ---------------------------------------------------------------------------
// prep: convert weights to bf16; pad W_w [256,131] -> [256,160] with zeros.
// Also zeroes the 8 per-stream work counters (graph-replay safe: runs every
// launch, same stream, before k_attn).
// ---------------------------------------------------------------------------
__global__ void k_prep(const float* th, const float* ph, const float* gw, const float* Ww,
                       unsigned short* TW, unsigned short* PW, unsigned short* GW,
                       unsigned short* Wp, int* Cnt) {
    if (blockIdx.x == 0 && threadIdx.x < 16) Cnt[threadIdx.x] = 0;
    int i = blockIdx.x * 256 + threadIdx.x;
    if (i < 32768) {
        TW[i] = f2bf(th[i]);
    } else if (i < 65536) {
        PW[i - 32768] = f2bf(ph[i - 32768]);
    } else if (i < 98304) {
        GW[i - 65536] = f2bf(gw[i - 65536]);
    } else if (i < 98304 + 256 * 160) {
        int j = i - 98304;
        int oc = j / 160, k = j - oc * 160;
        Wp[j] = (k < 131) ? f2bf(Ww[oc * 131 + k]) : (unsigned short)0;
    }
}

// ---------------------------------------------------------------------------
// xt: transpose x [n][c][px] fp32 -> xT [n][px][c] bf16 (coalesced both sides)
// tile: 64 px x 32 c per WG
// ---------------------------------------------------------------------------
__launch_bounds__(256)
__global__ void k_xt(const float* __restrict__ x, unsigned short* __restrict__ xT) {
    __shared__ unsigned short Xs[64][40];   // [px][c], stride 40 -> 16B-aligned rows
    int tid = threadIdx.x;
    int n = blockIdx.y;
    int px0 = (blockIdx.x & 255) * 64;
    int c0 = (blockIdx.x >> 8) * 32;
    #pragma unroll
    for (int p = 0; p < 2; ++p) {
        int c = c0 + p * 16 + (tid >> 4);
        int l = tid & 15;
        const float* src = x + (((size_t)(n * 256 + c)) << 14) + px0 + 4 * l;
        float4 v = *(const float4*)src;
        int cc = c - c0;
        Xs[4 * l + 0][cc] = us(v.x);
        Xs[4 * l + 1][cc] = us(v.y);
        Xs[4 * l + 2][cc] = us(v.z);
        Xs[4 * l + 3][cc] = us(v.w);
    }
    __syncthreads();
    int px = tid >> 2, c8 = (tid & 3) * 8;
    short8 row = *(const short8*)&Xs[px][c8];
    *(short8*)(xT + (((size_t)n << 14) + px0 + px) * 256 + c0 + c8) = row;
}

// ---------------------------------------------------------------------------
// poolT: 3x3/stride2/pad1 avgpool of x, output TRANSPOSED bf16 xpT[n][key][c]
// tile: 32 keys (one hd row) x 32 c per WG
// ---------------------------------------------------------------------------
__launch_bounds__(256)
__global__ void k_poolT(const float* __restrict__ x, unsigned short* __restrict__ xpT) {
    __shared__ unsigned short P[32][40];    // [wd][c]
    int tid = threadIdx.x;
    int n = blockIdx.y;
    int r = blockIdx.x & 127;               // t = r>>5, hd = r&31
    int c0 = (blockIdx.x >> 7) * 32;
    int t = r >> 5, hd = r & 31;
    int wd = tid & 31;
    int cg = (tid >> 5) * 4;
    int h0 = 2 * hd - 1, w0 = 2 * wd - 1;
    #pragma unroll
    for (int jj = 0; jj < 4; ++jj) {
        int c = c0 + cg + jj;
        const float* base = x + (((size_t)(n * 256 + c) * 4 + t) << 12);
        float s = 0.f;
        #pragma unroll
        for (int dh = 0; dh < 3; ++dh) {
            int h = h0 + dh;
            if ((unsigned)h < 64u) {
                const float* row = base + h * 64;
                #pragma unroll
                for (int dw = 0; dw < 3; ++dw) {
                    int w = w0 + dw;
                    if ((unsigned)w < 64u) s += row[w];
                }
            }
        }
        P[wd][cg + jj] = us(s * (1.f / 9.f));
    }
    __syncthreads();
    int key = r * 32 + (tid >> 3);
    int cc = (tid & 7) * 4;
    uint2 w = *(const uint2*)&P[tid >> 3][cc];
    *(uint2*)(xpT + (((size_t)n << 12) + key) * 256 + c0 + cc) = w;
}

// ---------------------------------------------------------------------------
// conv_q: Q[n*16384+px][ic] = sum_c xT[px][c]*theta_w[ic][c] + theta_b[ic]
// B-fragments are single b128 loads from xT (c-contiguous).
// ---------------------------------------------------------------------------
__launch_bounds__(256)
__global__ void k_convq(const unsigned short* __restrict__ xT, const unsigned short* __restrict__ TW,
                        const float* __restrict__ tb, unsigned short* __restrict__ Q) {
    __shared__ unsigned short Qs[4][16][132];   // [wave][px][ic], +4 pad
    int tid = threadIdx.x, wid = tid >> 6, lane = tid & 63, quad = lane >> 4, l16 = lane & 15;
    int n = blockIdx.y;
    int px0 = blockIdx.x * 64 + wid * 16;
    const unsigned short* xb = xT + (((size_t)n << 14) + px0 + l16) * 256;
    floatx4 acc[8];
    #pragma unroll
    for (int i = 0; i < 8; ++i) acc[i] = (floatx4)0.f;
    for (int kc = 0; kc < 8; ++kc) {
        int cbase = kc * 32 + quad * 8;
        short8 b = *(const short8*)(xb + cbase);
        #pragma unroll
        for (int mt = 0; mt < 8; ++mt) {
            short8 a = *(const short8*)(TW + (mt * 16 + l16) * 256 + cbase);
            acc[mt] = MFMA16(a, b, acc[mt]);
        }
    }
    #pragma unroll
    for (int mt = 0; mt < 8; ++mt) {
        int ic = mt * 16 + quad * 4;
        uint2 w;
        w.x = pkfast(acc[mt][0] + tb[ic], acc[mt][1] + tb[ic + 1]);
        w.y = pkfast(acc[mt][2] + tb[ic + 2], acc[mt][3] + tb[ic + 3]);
        *(uint2*)&Qs[wid][l16][ic] = w;
    }
    #pragma unroll
    for (int i = 0; i < 4; ++i) {
        int pxl = i * 4 + quad;
        short8 row = *(const short8*)&Qs[wid][pxl][l16 * 8];
        *(short8*)(Q + ((((size_t)n << 14) + px0 + pxl) << 7) + l16 * 8) = row;
    }
}

// ---------------------------------------------------------------------------
// conv_kv v2: 32 keys/WG (grid 256 = full GPU). Waves 0,1: K (phi); waves 2,3:
// V (g). B-frags = b128 loads from xpT. Writes St chunk half-images.
// ---------------------------------------------------------------------------
__launch_bounds__(256)
__global__ void k_convkv(const unsigned short* __restrict__ xpT,
                         const unsigned short* __restrict__ PW, const float* __restrict__ pb,
                         const unsigned short* __restrict__ GW, const float* __restrict__ gb,
                         unsigned short* __restrict__ Stg) {
    __shared__ unsigned short Ks[2][16][132];
    __shared__ unsigned short Vs[32][132];
    int tid = threadIdx.x, wid = tid >> 6, lane = tid & 63, quad = lane >> 4, l16 = lane & 15;
    int n = blockIdx.y;
    int c32 = blockIdx.x;                 // 32-key tile index
    int chunk = c32 >> 1, half = c32 & 1;
    int k0 = c32 * 32;
    int role = wid >> 1, kg = wid & 1;    // role 0 = K(phi), 1 = V(g)
    int key = k0 + kg * 16 + l16;
    unsigned short* sc = Stg + (size_t)(n * 64 + chunk) * CHUNK_SHORTS;
    const unsigned short* xb = xpT + (((size_t)n << 12) + key) * 256;
    const unsigned short* W = role ? GW : PW;
    const float* bias = role ? gb : pb;
    floatx4 acc[8];
    #pragma unroll
    for (int i = 0; i < 8; ++i) acc[i] = (floatx4)0.f;
    for (int kc = 0; kc < 8; ++kc) {
        int cbase = kc * 32 + quad * 8;
        short8 b = *(const short8*)(xb + cbase);
        #pragma unroll
        for (int mt = 0; mt < 8; ++mt) {
            short8 a = *(const short8*)(W + (mt * 16 + l16) * 256 + cbase);
            acc[mt] = MFMA16(a, b, acc[mt]);
        }
    }
    int hd = (key >> 5) & 31, wdd = key & 31;
    float frac = ((hd == 0) ? 2.f : 3.f) * ((wdd == 0) ? 2.f : 3.f) * (1.f / 9.f);

    if (role == 0) {
        // K epilogue: per-wave transpose, coalesced b128 stores into St K rows
        #pragma unroll
        for (int mt = 0; mt < 8; ++mt) {
            int ic = mt * 16 + quad * 4;
            uint2 w;
            w.x = pkfast(acc[mt][0] + bias[ic] * frac, acc[mt][1] + bias[ic + 1] * frac);
            w.y = pkfast(acc[mt][2] + bias[ic + 2] * frac, acc[mt][3] + bias[ic + 3] * frac);
            *(uint2*)&Ks[kg][l16][ic] = w;
        }
        #pragma unroll
        for (int i = 0; i < 4; ++i) {
            int pxl = i * 4 + quad;
            short8 row = *(const short8*)&Ks[kg][pxl][l16 * 8];
            *(short8*)(sc + (half * 32 + kg * 16 + pxl) * 136 + l16 * 8) = row;
        }
    } else {
        // V: write C-tile to WG-shared [key][ic] buffer
        #pragma unroll
        for (int mt = 0; mt < 8; ++mt) {
            int ic = mt * 16 + quad * 4;
            uint2 w;
            w.x = pkfast(acc[mt][0] + bias[ic] * frac, acc[mt][1] + bias[ic + 1] * frac);
            w.y = pkfast(acc[mt][2] + bias[ic + 2] * frac, acc[mt][3] + bias[ic + 3] * frac);
            *(uint2*)&Vs[kg * 16 + l16][ic] = w;
        }
    }
    __syncthreads();
    // V transpose-write: 128 ic rows x 32 keys -> St V half-rows (b128)
    #pragma unroll
    for (int it2 = 0; it2 < 2; ++it2) {
        int ic = it2 * 64 + (tid >> 2);
        int kk = (tid & 3) * 8;
        uint4v w;
        #pragma unroll
        for (int j = 0; j < 4; ++j) {
            unsigned s0 = Vs[kk + 2 * j][ic];
            unsigned s1 = Vs[kk + 2 * j + 1][ic];
            w[j] = s0 | (s1 << 16);
        }
        *(uint4v*)(sc + VOFF_SHORTS + ic * 72 + half * 32 + kk) = w;
    }
    // grid channels (128..130) and zero rows (131..159): 32 rows x 32 keys
    #pragma unroll
    for (int it = 0; it < 4; ++it) {
        int e = it * 256 + tid;
        int row = 128 + (e >> 5);
        int kl = e & 31;
        int kk = k0 + kl;
        int t = kk >> 10, hh = (kk >> 5) & 31, ww = kk & 31;
        unsigned short v = 0;
        if (row == 128) v = f2bf(((float)t * (1.f / 1.5f) - 1.f) * 0.1f);
        else if (row == 129) v = f2bf((float)hh * (1.f / 15.5f) - 1.f);
        else if (row == 130) v = f2bf((float)ww * (1.f / 7.75f) - 2.f);
        sc[VOFF_SHORTS + row * 72 + half * 32 + kl] = v;
    }
}

// ---------------------------------------------------------------------------
// softmax + PV for one 32-key subtile (in-register P transpose)
// ---------------------------------------------------------------------------
__device__ __forceinline__ void softmax_pv(const floatx16 st, int ks,
                                           const short (*Vlds)[72], floatx16* O,
                                           float& lacc, int l32, int half) {
    unsigned u[8];
    #pragma unroll
    for (int a = 0; a < 4; ++a) {
        float p0 = exp2f(fmaf(st[4 * a + 0], 1.44269504f, -17.3123404907f));
        float p1 = exp2f(fmaf(st[4 * a + 1], 1.44269504f, -17.3123404907f));
        float p2 = exp2f(fmaf(st[4 * a + 2], 1.44269504f, -17.3123404907f));
        float p3 = exp2f(fmaf(st[4 * a + 3], 1.44269504f, -17.3123404907f));
        lacc += (p0 + p1) + (p2 + p3);
        u[2 * a] = pkfast(p0, p1);
        u[2 * a + 1] = pkfast(p2, p3);
    }
    unsigned xu[8];
    #pragma unroll
    for (int g = 0; g < 8; ++g) xu[g] = (unsigned)__shfl_xor((int)u[g], 32);
    uint4v pw0, pw1;
    pw0[0] = half ? xu[2] : u[0];
    pw0[1] = half ? xu[3] : u[1];
    pw0[2] = half ? u[2] : xu[0];
    pw0[3] = half ? u[3] : xu[1];
    pw1[0] = half ? xu[6] : u[4];
    pw1[1] = half ? xu[7] : u[5];
    pw1[2] = half ? u[6] : xu[4];
    pw1[3] = half ? u[7] : xu[5];
    short8 pf0 = __builtin_bit_cast(short8, pw0);
    short8 pf1 = __builtin_bit_cast(short8, pw1);
    #pragma unroll
    for (int vt = 0; vt < 5; ++vt) {
        short8 vf0 = *(const short8*)&Vlds[vt * 32 + l32][ks * 32 + half * 8];
        O[vt] = MFMA32(vf0, pf0, O[vt]);
        short8 vf1 = *(const short8*)&Vlds[vt * 32 + l32][ks * 32 + 16 + half * 8];
        O[vt] = MFMA32(vf1, pf1, O[vt]);
    }
}

// full compile-time scheduling fence (rule #18: raw s_barrier is not a fence)
#define SFENCE() __builtin_amdgcn_sched_barrier(0)

// ---------------------------------------------------------------------------
// flash attention v13: v12 (XCD-exact stream claiming, FETCH 21MB verified)
// with the work-id broadcast moved INTO the staging buffer Sh: R6's extra
// `__shared__ int` pushed LDS 40960->41472, dropping residency 4->3 blocks/CU
// and creating a 256-block tail (occupancy 20%). Claim is read from Sh[0..3]
// and double-barriered before the first STAGE_K overwrites it. LDS = exactly
// 40960 -> 4 blocks/CU, all 1024 blocks co-resident, no tail.
// ---------------------------------------------------------------------------
__launch_bounds__(256, 4)
__global__ void k_attn(const unsigned short* __restrict__ Q,
                       const unsigned char* __restrict__ Stg,
                       unsigned short* __restrict__ Y, float* __restrict__ L,
                       int* __restrict__ Cnt) {
    __shared__ __align__(16) char Sh[CHUNK_BYTES];
    int tid = threadIdx.x, wid = tid >> 6, lane = tid & 63;
    int l32 = lane & 31, half = lane >> 5;

    if (tid == 0) {
        unsigned xcc;
        asm volatile("s_getreg_b32 %0, hwreg(HW_REG_XCC_ID)" : "=s"(xcc));
        int s = (int)(xcc & 7u);
        int t = atomicAdd(&Cnt[s], 1);
        if (t >= 128) {
            // counter>=128 <=> that stream fully claimed; scan finds the rest.
            // (values 0..127 are handed out in arrival order, so every tile
            // is claimed exactly once; 1024 blocks == 1024 tiles => no
            // starvation.)
            #pragma unroll 1
            for (int k = 1; k <= 8; ++k) {
                int s2 = (s + k) & 7;
                t = atomicAdd(&Cnt[s2], 1);
                if (t < 128) { s = s2; break; }
            }
        }
        *(volatile int*)Sh = (s << 16) | (t & 0xffff);
    }
    __syncthreads();
    int swork = *(volatile int*)Sh;
    __syncthreads();            // all threads have read before staging clobbers Sh
    int strm = swork >> 16;
    int qb = swork & 0xffff;
    int n = strm & 1, sp = strm >> 1;
    int c0 = (sp * 64) / SPLITS, c1 = ((sp + 1) * 64) / SPLITS;
    int nch = c1 - c0;
    int q0 = qb * 128 + wid * 32;

    const unsigned short* Qr = Q + ((((size_t)n << 14) + q0 + l32) << 7);
    short8 qf[8];
    #pragma unroll
    for (int kc = 0; kc < 8; ++kc) qf[kc] = *(const short8*)(Qr + kc * 16 + half * 8);

    floatx16 O[5];
    #pragma unroll
    for (int t = 0; t < 5; ++t) O[t] = (floatx16)0.f;
    float lacc = 0.f;

    const short (*Klds)[136] = (const short(*)[136])Sh;
    const short (*Vlds)[72] = (const short(*)[72])(Sh + 17408);

    const unsigned char* gbase = Stg + ((size_t)(n * 64 + c0)) * CHUNK_BYTES;
    int woff = wid << 10;           // wave-uniform LDS slice component
    int lgo = woff + lane * 16;     // per-lane global offset component

    // K bytes [0,17408): 4 full 4KB rounds + overlapped tail at 13312 (5 ops)
#define STAGE_K(gch) do { const unsigned char* g_ = (gch);                     \
        gload_lds16(g_ + 0 * 4096 + lgo, Sh + 0 * 4096 + woff);                \
        gload_lds16(g_ + 1 * 4096 + lgo, Sh + 1 * 4096 + woff);                \
        gload_lds16(g_ + 2 * 4096 + lgo, Sh + 2 * 4096 + woff);                \
        gload_lds16(g_ + 3 * 4096 + lgo, Sh + 3 * 4096 + woff);                \
        gload_lds16(g_ + 13312 + lgo,    Sh + 13312 + woff); } while (0)
    // V+pad bytes [17408,40960): 5 full rounds + overlapped tail at 36864 (6 ops)
#define STAGE_V(gch) do { const unsigned char* g_ = (gch);                     \
        gload_lds16(g_ + 17408 + 0 * 4096 + lgo, Sh + 17408 + 0 * 4096 + woff);\
        gload_lds16(g_ + 17408 + 1 * 4096 + lgo, Sh + 17408 + 1 * 4096 + woff);\
        gload_lds16(g_ + 17408 + 2 * 4096 + lgo, Sh + 17408 + 2 * 4096 + woff);\
        gload_lds16(g_ + 17408 + 3 * 4096 + lgo, Sh + 17408 + 3 * 4096 + woff);\
        gload_lds16(g_ + 17408 + 4 * 4096 + lgo, Sh + 17408 + 4 * 4096 + woff);\
        gload_lds16(g_ + 36864 + lgo,            Sh + 36864 + woff); } while (0)

    // prologue: K(0)+V(0) issued; wait K only (V flies under first QK^T)
    STAGE_K(gbase);
    STAGE_V(gbase);
    SFENCE();
    asm volatile("s_waitcnt vmcnt(6)" ::: "memory");
    SFENCE();
    __builtin_amdgcn_s_barrier();
    SFENCE();

    for (int it = 0; it < nch; ++it) {
        // invariant: K(it) resident in all waves; own V(it) loads in flight
        floatx16 st0 = (floatx16)0.f, st1 = (floatx16)0.f;
        #pragma unroll
        for (int kc = 0; kc < 8; ++kc) {
            short8 kf0 = *(const short8*)&Klds[l32][kc * 16 + half * 8];
            st0 = MFMA32(kf0, qf[kc], st0);
            short8 kf1 = *(const short8*)&Klds[32 + l32][kc * 16 + half * 8];
            st1 = MFMA32(kf1, qf[kc], st1);
        }
        SFENCE();                                      // pin K ds_reads + MFMAs above
        asm volatile("s_waitcnt vmcnt(0)" ::: "memory");   // own V(it) landed
        SFENCE();
        __builtin_amdgcn_s_barrier();                  // all: V ready & K reads done
        SFENCE();                                      // block V-read hoist above bar
        if (it + 1 < nch) STAGE_K(gbase + (size_t)(it + 1) * CHUNK_BYTES);
        softmax_pv(st0, 0, Vlds, O, lacc, l32, half);
        softmax_pv(st1, 1, Vlds, O, lacc, l32, half);
        SFENCE();                                      // pin V ds_reads above
        __builtin_amdgcn_s_barrier();                  // all: V reads done
        SFENCE();
        if (it + 1 < nch) {
            STAGE_V(gbase + (size_t)(it + 1) * CHUNK_BYTES);
            SFENCE();
            asm volatile("s_waitcnt vmcnt(6)" ::: "memory"); // own K(it+1) landed
            SFENCE();
        }
        __builtin_amdgcn_s_barrier();                  // all: K(it+1) ready
        SFENCE();                                      // block next K-read hoist
    }
#undef STAGE_K
#undef STAGE_V

    float lt = lacc + __shfl_xor(lacc, 32);
    int slab = sp * 2 + n;
    unsigned short* Yb = Y + ((((size_t)slab << 14) + q0 + l32) * 160);
    #pragma unroll
    for (int vt = 0; vt < 5; ++vt)
        #pragma unroll
        for (int g = 0; g < 4; ++g) {
            int vd = vt * 32 + 8 * g + 4 * half;
            uint2 w;
            w.x = pkfast(O[vt][4 * g], O[vt][4 * g + 1]);
            w.y = pkfast(O[vt][4 * g + 2], O[vt][4 * g + 3]);
            *(uint2*)(Yb + vd) = w;
        }
    if (lane < 32) L[(((size_t)slab) << 14) + q0 + lane] = lt;
}

// ---------------------------------------------------------------------------
// final conv + split combine + normalize
// ---------------------------------------------------------------------------
__launch_bounds__(256)
__global__ void k_convf(const unsigned short* __restrict__ Y, const float* __restrict__ L,
                        const unsigned short* __restrict__ Wp, const float* __restrict__ Wb,
                        float* __restrict__ out) {
    int tid = threadIdx.x, wid = tid >> 6, lane = tid & 63, quad = lane >> 4, l16 = lane & 15;
    int n = blockIdx.y;
    int p0 = blockIdx.x * 64;
    floatx4 acc[4][4];
    #pragma unroll
    for (int i = 0; i < 4; ++i)
        #pragma unroll
        for (int j = 0; j < 4; ++j) acc[i][j] = (floatx4)0.f;
    for (int kc = 0; kc < 5; ++kc) {
        int cb = kc * 32 + quad * 8;
        short8 a[4];
        #pragma unroll
        for (int mt = 0; mt < 4; ++mt)
            a[mt] = *(const short8*)(Wp + (size_t)(wid * 64 + mt * 16 + l16) * 160 + cb);
        #pragma unroll
        for (int sp = 0; sp < SPLITS; ++sp) {
            const unsigned short* Yb = Y + ((((size_t)(sp * 2 + n)) << 14) + p0) * 160;
            #pragma unroll
            for (int nt = 0; nt < 4; ++nt) {
                short8 b = *(const short8*)(Yb + (size_t)(nt * 16 + l16) * 160 + cb);
                #pragma unroll
                for (int mt = 0; mt < 4; ++mt) acc[mt][nt] = MFMA16(a[mt], b, acc[mt][nt]);
            }
        }
    }
    float linv[4];
    #pragma unroll
    for (int nt = 0; nt < 4; ++nt) {
        int p = p0 + nt * 16 + l16;
        float ls = 0.f;
        #pragma unroll
        for (int sp = 0; sp < SPLITS; ++sp) ls += L[(((size_t)(sp * 2 + n)) << 14) + p];
        linv[nt] = 1.f / ls;
    }
    #pragma unroll
    for (int mt = 0; mt < 4; ++mt)
        #pragma unroll
        for (int r = 0; r < 4; ++r) {
            int oc = wid * 64 + mt * 16 + quad * 4 + r;
            float bb = Wb[oc];
            float* orow = out + ((((size_t)n << 8) + oc) << 14) + p0;
            #pragma unroll
            for (int nt = 0; nt < 4; ++nt)
                orow[nt * 16 + l16] = acc[mt][nt][r] * linv[nt] + bb;
        }
}

// ---------------------------------------------------------------------------
extern "C" void kernel_launch(void* const* d_in, const int* in_sizes, int n_in,
                              void* d_out, int out_size, void* d_ws, size_t ws_size,
                              hipStream_t stream) {
    (void)in_sizes; (void)n_in; (void)out_size; (void)ws_size;
    const float* x   = (const float*)d_in[0];
    const float* thw = (const float*)d_in[1];
    const float* thb = (const float*)d_in[2];
    const float* phw = (const float*)d_in[3];
    const float* phb = (const float*)d_in[4];
    const float* gw_ = (const float*)d_in[5];
    const float* gb_ = (const float*)d_in[6];
    const float* Ww  = (const float*)d_in[7];
    const float* Wb  = (const float*)d_in[8];
    float* out = (float*)d_out;

    char* ws = (char*)d_ws;
    size_t off = 0;
    auto alloc = [&](size_t b) { size_t o = off; off += (b + 255) & ~(size_t)255; return o; };
    int*            Cnt = (int*)(ws + alloc(64));
    unsigned short* TW = (unsigned short*)(ws + alloc(32768 * 2));
    unsigned short* PW = (unsigned short*)(ws + alloc(32768 * 2));
    unsigned short* GW = (unsigned short*)(ws + alloc(32768 * 2));
    unsigned short* Wp = (unsigned short*)(ws + alloc(40960 * 2));
    unsigned short* Qb = (unsigned short*)(ws + alloc((size_t)32768 * 128 * 2));
    unsigned short* St = (unsigned short*)(ws + alloc((size_t)2 * 64 * CHUNK_BYTES));
    float*          Lb = (float*)(ws + alloc((size_t)SPLITS * 2 * 16384 * 4));
    // Y: [split*2+n][p][160]. xT (16.78 MB) + xpT (4.19 MB) alias into Y's
    // region: SPLITS=4 -> ybytes = 41.9 MB >= xT+xpT (20.97 MB). Both are
    // dead before attn writes Y (same-stream ordering), convf reads Y last.
    size_t ybytes = (size_t)SPLITS * 2 * 16384 * 160 * 2;
    unsigned short* Yb  = (unsigned short*)(ws + alloc(ybytes));
    unsigned short* xT  = Yb;
    unsigned short* xpT = (unsigned short*)((char*)Yb + (size_t)2 * 16384 * 256 * 2);

    k_prep<<<(139264 + 255) / 256, 256, 0, stream>>>(thw, phw, gw_, Ww, TW, PW, GW, Wp, Cnt);
    k_xt<<<dim3(2048, 2), 256, 0, stream>>>(x, xT);
    k_poolT<<<dim3(1024, 2), 256, 0, stream>>>(x, xpT);
    k_convq<<<dim3(256, 2), 256, 0, stream>>>(xT, TW, thb, Qb);
    k_convkv<<<dim3(128, 2), 256, 0, stream>>>(xpT, PW, phb, GW, gb_, St);
    k_attn<<<dim3(1024, 1, 1), 256, 0, stream>>>(Qb, (const unsigned char*)St, Yb, Lb, Cnt);
    k_convf<<<dim3(256, 2), 256, 0, stream>>>(Yb, Lb, Wp, Wb, out);
}

// Round 8
// 261.967 us; speedup vs baseline: 1.5583x; 1.5583x over previous
//
#include <hip/hip_runtime.h>
#include <stdint.h>

typedef short short8 __attribute__((ext_vector_type(8)));
typedef float floatx4 __attribute__((ext_vector_type(4)));
typedef float floatx16 __attribute__((ext_vector_type(16)));
typedef unsigned uint4v __attribute__((ext_vector_type(4)));

#define MFMA16(a, b, c) __builtin_amdgcn_mfma_f32_16x16x32_bf16((a), (b), (c), 0, 0, 0)
#define MFMA32(a, b, c) __builtin_amdgcn_mfma_f32_32x32x16_bf16((a), (b), (c), 0, 0, 0)

#define SPLITS 3
// staged chunk image: K 64x136 shorts (17408 B) | V 160x72 shorts (23040 B) | pad 512 B
#define CHUNK_BYTES 40960
#define CHUNK_SHORTS 20480
#define VOFF_SHORTS 8704

typedef __attribute__((address_space(1))) const void* gas1_cp;
typedef __attribute__((address_space(3))) void* las3_p;

__device__ __forceinline__ void gload_lds16(const void* g, void* l) {
    __builtin_amdgcn_global_load_lds((gas1_cp)g, (las3_p)l, 16, 0, 0);
}

__device__ __forceinline__ unsigned short f2bf(float f) {
    union { float f; unsigned u; } v; v.f = f;
    unsigned u = v.u;
    unsigned r = (u + 0x7FFFu + ((u >> 16) & 1u)) >> 16;
    return (unsigned short)r;
}
// round-half-up single float -> bf16 (bit-identical to pkfast halves)
__device__ __forceinline__ unsigned short us(float f) {
    return (unsigned short)((__float_as_uint(f) + 0x8000u) >> 16);
}
// fast pack: round-half-up both floats to bf16, pack lo|hi<<16 in one v_perm
__device__ __forceinline__ unsigned pkfast(float lo, float hi) {
    unsigned a = __float_as_uint(lo) + 0x8000u;
    unsigned b = __float_as_uint(hi) + 0x8000u;
    return __builtin_amdgcn_perm(b, a, 0x07060302u);
}

// ---------------------------------------------------------------------------
// prep: convert weights to bf16; pad W_w [256,131] -> [256,160] with zeros
// ---------------------------------------------------------------------------
__global__ void k_prep(const float* th, const float* ph, const float* gw, const float* Ww,
                       unsigned short* TW, unsigned short* PW, unsigned short* GW,
                       unsigned short* Wp) {
    int i = blockIdx.x * 256 + threadIdx.x;
    if (i < 32768) {
        TW[i] = f2bf(th[i]);
    } else if (i < 65536) {
        PW[i - 32768] = f2bf(ph[i - 32768]);
    } else if (i < 98304) {
        GW[i - 65536] = f2bf(gw[i - 65536]);
    } else if (i < 98304 + 256 * 160) {
        int j = i - 98304;
        int oc = j / 160, k = j - oc * 160;
        Wp[j] = (k < 131) ? f2bf(Ww[oc * 131 + k]) : (unsigned short)0;
    }
}

// ---------------------------------------------------------------------------
// xt: transpose x [n][c][px] fp32 -> xT [n][px][c] bf16 (coalesced both sides)
// tile: 64 px x 32 c per WG
// ---------------------------------------------------------------------------
__launch_bounds__(256)
__global__ void k_xt(const float* __restrict__ x, unsigned short* __restrict__ xT) {
    __shared__ unsigned short Xs[64][40];   // [px][c], stride 40 -> 16B-aligned rows
    int tid = threadIdx.x;
    int n = blockIdx.y;
    int px0 = (blockIdx.x & 255) * 64;
    int c0 = (blockIdx.x >> 8) * 32;
    #pragma unroll
    for (int p = 0; p < 2; ++p) {
        int c = c0 + p * 16 + (tid >> 4);
        int l = tid & 15;
        const float* src = x + (((size_t)(n * 256 + c)) << 14) + px0 + 4 * l;
        float4 v = *(const float4*)src;
        int cc = c - c0;
        Xs[4 * l + 0][cc] = us(v.x);
        Xs[4 * l + 1][cc] = us(v.y);
        Xs[4 * l + 2][cc] = us(v.z);
        Xs[4 * l + 3][cc] = us(v.w);
    }
    __syncthreads();
    int px = tid >> 2, c8 = (tid & 3) * 8;
    short8 row = *(const short8*)&Xs[px][c8];
    *(short8*)(xT + (((size_t)n << 14) + px0 + px) * 256 + c0 + c8) = row;
}

// ---------------------------------------------------------------------------
// poolT: 3x3/stride2/pad1 avgpool of x, output TRANSPOSED bf16 xpT[n][key][c]
// tile: 32 keys (one hd row) x 32 c per WG
// ---------------------------------------------------------------------------
__launch_bounds__(256)
__global__ void k_poolT(const float* __restrict__ x, unsigned short* __restrict__ xpT) {
    __shared__ unsigned short P[32][40];    // [wd][c]
    int tid = threadIdx.x;
    int n = blockIdx.y;
    int r = blockIdx.x & 127;               // t = r>>5, hd = r&31
    int c0 = (blockIdx.x >> 7) * 32;
    int t = r >> 5, hd = r & 31;
    int wd = tid & 31;
    int cg = (tid >> 5) * 4;
    int h0 = 2 * hd - 1, w0 = 2 * wd - 1;
    #pragma unroll
    for (int jj = 0; jj < 4; ++jj) {
        int c = c0 + cg + jj;
        const float* base = x + (((size_t)(n * 256 + c) * 4 + t) << 12);
        float s = 0.f;
        #pragma unroll
        for (int dh = 0; dh < 3; ++dh) {
            int h = h0 + dh;
            if ((unsigned)h < 64u) {
                const float* row = base + h * 64;
                #pragma unroll
                for (int dw = 0; dw < 3; ++dw) {
                    int w = w0 + dw;
                    if ((unsigned)w < 64u) s += row[w];
                }
            }
        }
        P[wd][cg + jj] = us(s * (1.f / 9.f));
    }
    __syncthreads();
    int key = r * 32 + (tid >> 3);
    int cc = (tid & 7) * 4;
    uint2 w = *(const uint2*)&P[tid >> 3][cc];
    *(uint2*)(xpT + (((size_t)n << 12) + key) * 256 + c0 + cc) = w;
}

// ---------------------------------------------------------------------------
// conv_q: Q[n*16384+px][ic] = sum_c xT[px][c]*theta_w[ic][c] + theta_b[ic]
// B-fragments are single b128 loads from xT (c-contiguous).
// ---------------------------------------------------------------------------
__launch_bounds__(256)
__global__ void k_convq(const unsigned short* __restrict__ xT, const unsigned short* __restrict__ TW,
                        const float* __restrict__ tb, unsigned short* __restrict__ Q) {
    __shared__ unsigned short Qs[4][16][132];   // [wave][px][ic], +4 pad
    int tid = threadIdx.x, wid = tid >> 6, lane = tid & 63, quad = lane >> 4, l16 = lane & 15;
    int n = blockIdx.y;
    int px0 = blockIdx.x * 64 + wid * 16;
    const unsigned short* xb = xT + (((size_t)n << 14) + px0 + l16) * 256;
    floatx4 acc[8];
    #pragma unroll
    for (int i = 0; i < 8; ++i) acc[i] = (floatx4)0.f;
    for (int kc = 0; kc < 8; ++kc) {
        int cbase = kc * 32 + quad * 8;
        short8 b = *(const short8*)(xb + cbase);
        #pragma unroll
        for (int mt = 0; mt < 8; ++mt) {
            short8 a = *(const short8*)(TW + (mt * 16 + l16) * 256 + cbase);
            acc[mt] = MFMA16(a, b, acc[mt]);
        }
    }
    #pragma unroll
    for (int mt = 0; mt < 8; ++mt) {
        int ic = mt * 16 + quad * 4;
        uint2 w;
        w.x = pkfast(acc[mt][0] + tb[ic], acc[mt][1] + tb[ic + 1]);
        w.y = pkfast(acc[mt][2] + tb[ic + 2], acc[mt][3] + tb[ic + 3]);
        *(uint2*)&Qs[wid][l16][ic] = w;
    }
    #pragma unroll
    for (int i = 0; i < 4; ++i) {
        int pxl = i * 4 + quad;
        short8 row = *(const short8*)&Qs[wid][pxl][l16 * 8];
        *(short8*)(Q + ((((size_t)n << 14) + px0 + pxl) << 7) + l16 * 8) = row;
    }
}

// ---------------------------------------------------------------------------
// conv_kv v2: 32 keys/WG (grid 256 = full GPU). Waves 0,1: K (phi); waves 2,3:
// V (g). B-frags = b128 loads from xpT. Writes St chunk half-images.
// ---------------------------------------------------------------------------
__launch_bounds__(256)
__global__ void k_convkv(const unsigned short* __restrict__ xpT,
                         const unsigned short* __restrict__ PW, const float* __restrict__ pb,
                         const unsigned short* __restrict__ GW, const float* __restrict__ gb,
                         unsigned short* __restrict__ Stg) {
    __shared__ unsigned short Ks[2][16][132];
    __shared__ unsigned short Vs[32][132];
    int tid = threadIdx.x, wid = tid >> 6, lane = tid & 63, quad = lane >> 4, l16 = lane & 15;
    int n = blockIdx.y;
    int c32 = blockIdx.x;                 // 32-key tile index
    int chunk = c32 >> 1, half = c32 & 1;
    int k0 = c32 * 32;
    int role = wid >> 1, kg = wid & 1;    // role 0 = K(phi), 1 = V(g)
    int key = k0 + kg * 16 + l16;
    unsigned short* sc = Stg + (size_t)(n * 64 + chunk) * CHUNK_SHORTS;
    const unsigned short* xb = xpT + (((size_t)n << 12) + key) * 256;
    const unsigned short* W = role ? GW : PW;
    const float* bias = role ? gb : pb;
    floatx4 acc[8];
    #pragma unroll
    for (int i = 0; i < 8; ++i) acc[i] = (floatx4)0.f;
    for (int kc = 0; kc < 8; ++kc) {
        int cbase = kc * 32 + quad * 8;
        short8 b = *(const short8*)(xb + cbase);
        #pragma unroll
        for (int mt = 0; mt < 8; ++mt) {
            short8 a = *(const short8*)(W + (mt * 16 + l16) * 256 + cbase);
            acc[mt] = MFMA16(a, b, acc[mt]);
        }
    }
    int hd = (key >> 5) & 31, wdd = key & 31;
    float frac = ((hd == 0) ? 2.f : 3.f) * ((wdd == 0) ? 2.f : 3.f) * (1.f / 9.f);

    if (role == 0) {
        // K epilogue: per-wave transpose, coalesced b128 stores into St K rows
        #pragma unroll
        for (int mt = 0; mt < 8; ++mt) {
            int ic = mt * 16 + quad * 4;
            uint2 w;
            w.x = pkfast(acc[mt][0] + bias[ic] * frac, acc[mt][1] + bias[ic + 1] * frac);
            w.y = pkfast(acc[mt][2] + bias[ic + 2] * frac, acc[mt][3] + bias[ic + 3] * frac);
            *(uint2*)&Ks[kg][l16][ic] = w;
        }
        #pragma unroll
        for (int i = 0; i < 4; ++i) {
            int pxl = i * 4 + quad;
            short8 row = *(const short8*)&Ks[kg][pxl][l16 * 8];
            *(short8*)(sc + (half * 32 + kg * 16 + pxl) * 136 + l16 * 8) = row;
        }
    } else {
        // V: write C-tile to WG-shared [key][ic] buffer
        #pragma unroll
        for (int mt = 0; mt < 8; ++mt) {
            int ic = mt * 16 + quad * 4;
            uint2 w;
            w.x = pkfast(acc[mt][0] + bias[ic] * frac, acc[mt][1] + bias[ic + 1] * frac);
            w.y = pkfast(acc[mt][2] + bias[ic + 2] * frac, acc[mt][3] + bias[ic + 3] * frac);
            *(uint2*)&Vs[kg * 16 + l16][ic] = w;
        }
    }
    __syncthreads();
    // V transpose-write: 128 ic rows x 32 keys -> St V half-rows (b128)
    #pragma unroll
    for (int it2 = 0; it2 < 2; ++it2) {
        int ic = it2 * 64 + (tid >> 2);
        int kk = (tid & 3) * 8;
        uint4v w;
        #pragma unroll
        for (int j = 0; j < 4; ++j) {
            unsigned s0 = Vs[kk + 2 * j][ic];
            unsigned s1 = Vs[kk + 2 * j + 1][ic];
            w[j] = s0 | (s1 << 16);
        }
        *(uint4v*)(sc + VOFF_SHORTS + ic * 72 + half * 32 + kk) = w;
    }
    // grid channels (128..130) and zero rows (131..159): 32 rows x 32 keys
    #pragma unroll
    for (int it = 0; it < 4; ++it) {
        int e = it * 256 + tid;
        int row = 128 + (e >> 5);
        int kl = e & 31;
        int kk = k0 + kl;
        int t = kk >> 10, hh = (kk >> 5) & 31, ww = kk & 31;
        unsigned short v = 0;
        if (row == 128) v = f2bf(((float)t * (1.f / 1.5f) - 1.f) * 0.1f);
        else if (row == 129) v = f2bf((float)hh * (1.f / 15.5f) - 1.f);
        else if (row == 130) v = f2bf((float)ww * (1.f / 7.75f) - 2.f);
        sc[VOFF_SHORTS + row * 72 + half * 32 + kl] = v;
    }
}

// ---------------------------------------------------------------------------
// softmax + PV for one 32-key subtile (in-register P transpose)
// ---------------------------------------------------------------------------
__device__ __forceinline__ void softmax_pv(const floatx16 st, int ks,
                                           const short (*Vlds)[72], floatx16* O,
                                           float& lacc, int l32, int half) {
    unsigned u[8];
    #pragma unroll
    for (int a = 0; a < 4; ++a) {
        float p0 = exp2f(fmaf(st[4 * a + 0], 1.44269504f, -17.3123404907f));
        float p1 = exp2f(fmaf(st[4 * a + 1], 1.44269504f, -17.3123404907f));
        float p2 = exp2f(fmaf(st[4 * a + 2], 1.44269504f, -17.3123404907f));
        float p3 = exp2f(fmaf(st[4 * a + 3], 1.44269504f, -17.3123404907f));
        lacc += (p0 + p1) + (p2 + p3);
        u[2 * a] = pkfast(p0, p1);
        u[2 * a + 1] = pkfast(p2, p3);
    }
    unsigned xu[8];
    #pragma unroll
    for (int g = 0; g < 8; ++g) xu[g] = (unsigned)__shfl_xor((int)u[g], 32);
    uint4v pw0, pw1;
    pw0[0] = half ? xu[2] : u[0];
    pw0[1] = half ? xu[3] : u[1];
    pw0[2] = half ? u[2] : xu[0];
    pw0[3] = half ? u[3] : xu[1];
    pw1[0] = half ? xu[6] : u[4];
    pw1[1] = half ? xu[7] : u[5];
    pw1[2] = half ? u[6] : xu[4];
    pw1[3] = half ? u[7] : xu[5];
    short8 pf0 = __builtin_bit_cast(short8, pw0);
    short8 pf1 = __builtin_bit_cast(short8, pw1);
    #pragma unroll
    for (int vt = 0; vt < 5; ++vt) {
        short8 vf0 = *(const short8*)&Vlds[vt * 32 + l32][ks * 32 + half * 8];
        O[vt] = MFMA32(vf0, pf0, O[vt]);
        short8 vf1 = *(const short8*)&Vlds[vt * 32 + l32][ks * 32 + 16 + half * 8];
        O[vt] = MFMA32(vf1, pf1, O[vt]);
    }
}

// full compile-time scheduling fence (rule #18: raw s_barrier is not a fence)
#define SFENCE() __builtin_amdgcn_sched_barrier(0)

// ---------------------------------------------------------------------------
// flash attention v14: R3-verified K/V pipeline at the L2-safe operating
// point. Law from R0-R7: per-XCD staging working set = (blocks/XCD)*40KB must
// fit the 4MiB L2 (96*40KB=3.75MB fits; 128*40KB=5.12MB thrashes, FETCH
// 25MB->500MB). XCD-affinity tricks (bid%8, XCC_ID claiming) do NOT beat
// this law. So: SPLITS=3 -> grid 768 = exactly 3 blocks/CU, tail-free, with
// the counted-vmcnt pipeline removing the per-chunk drain stall.
// ---------------------------------------------------------------------------
__launch_bounds__(256, 3)
__global__ void k_attn(const unsigned short* __restrict__ Q,
                       const unsigned char* __restrict__ Stg,
                       unsigned short* __restrict__ Y, float* __restrict__ L) {
    __shared__ __align__(16) char Sh[CHUNK_BYTES];
    int tid = threadIdx.x, wid = tid >> 6, lane = tid & 63;
    int l32 = lane & 31, half = lane >> 5;
    int n = blockIdx.y, sp = blockIdx.z;
    int c0 = (sp * 64) / SPLITS, c1 = ((sp + 1) * 64) / SPLITS;
    int nch = c1 - c0;
    int q0 = blockIdx.x * 128 + wid * 32;

    const unsigned short* Qr = Q + ((((size_t)n << 14) + q0 + l32) << 7);
    short8 qf[8];
    #pragma unroll
    for (int kc = 0; kc < 8; ++kc) qf[kc] = *(const short8*)(Qr + kc * 16 + half * 8);

    floatx16 O[5];
    #pragma unroll
    for (int t = 0; t < 5; ++t) O[t] = (floatx16)0.f;
    float lacc = 0.f;

    const short (*Klds)[136] = (const short(*)[136])Sh;
    const short (*Vlds)[72] = (const short(*)[72])(Sh + 17408);

    const unsigned char* gbase = Stg + ((size_t)(n * 64 + c0)) * CHUNK_BYTES;
    int woff = wid << 10;           // wave-uniform LDS slice component
    int lgo = woff + lane * 16;     // per-lane global offset component

    // K bytes [0,17408): 4 full 4KB rounds + overlapped tail at 13312 (5 ops)
#define STAGE_K(gch) do { const unsigned char* g_ = (gch);                     \
        gload_lds16(g_ + 0 * 4096 + lgo, Sh + 0 * 4096 + woff);                \
        gload_lds16(g_ + 1 * 4096 + lgo, Sh + 1 * 4096 + woff);                \
        gload_lds16(g_ + 2 * 4096 + lgo, Sh + 2 * 4096 + woff);                \
        gload_lds16(g_ + 3 * 4096 + lgo, Sh + 3 * 4096 + woff);                \
        gload_lds16(g_ + 13312 + lgo,    Sh + 13312 + woff); } while (0)
    // V+pad bytes [17408,40960): 5 full rounds + overlapped tail at 36864 (6 ops)
#define STAGE_V(gch) do { const unsigned char* g_ = (gch);                     \
        gload_lds16(g_ + 17408 + 0 * 4096 + lgo, Sh + 17408 + 0 * 4096 + woff);\
        gload_lds16(g_ + 17408 + 1 * 4096 + lgo, Sh + 17408 + 1 * 4096 + woff);\
        gload_lds16(g_ + 17408 + 2 * 4096 + lgo, Sh + 17408 + 2 * 4096 + woff);\
        gload_lds16(g_ + 17408 + 3 * 4096 + lgo, Sh + 17408 + 3 * 4096 + woff);\
        gload_lds16(g_ + 17408 + 4 * 4096 + lgo, Sh + 17408 + 4 * 4096 + woff);\
        gload_lds16(g_ + 36864 + lgo,            Sh + 36864 + woff); } while (0)

    // prologue: K(0)+V(0) issued; wait K only (V flies under first QK^T)
    STAGE_K(gbase);
    STAGE_V(gbase);
    SFENCE();
    asm volatile("s_waitcnt vmcnt(6)" ::: "memory");
    SFENCE();
    __builtin_amdgcn_s_barrier();
    SFENCE();

    for (int it = 0; it < nch; ++it) {
        // invariant: K(it) resident in all waves; own V(it) loads in flight
        floatx16 st0 = (floatx16)0.f, st1 = (floatx16)0.f;
        #pragma unroll
        for (int kc = 0; kc < 8; ++kc) {
            short8 kf0 = *(const short8*)&Klds[l32][kc * 16 + half * 8];
            st0 = MFMA32(kf0, qf[kc], st0);
            short8 kf1 = *(const short8*)&Klds[32 + l32][kc * 16 + half * 8];
            st1 = MFMA32(kf1, qf[kc], st1);
        }
        SFENCE();                                      // pin K ds_reads + MFMAs above
        asm volatile("s_waitcnt vmcnt(0)" ::: "memory");   // own V(it) landed
        SFENCE();
        __builtin_amdgcn_s_barrier();                  // all: V ready & K reads done
        SFENCE();                                      // block V-read hoist above bar
        if (it + 1 < nch) STAGE_K(gbase + (size_t)(it + 1) * CHUNK_BYTES);
        softmax_pv(st0, 0, Vlds, O, lacc, l32, half);
        softmax_pv(st1, 1, Vlds, O, lacc, l32, half);
        SFENCE();                                      // pin V ds_reads above
        __builtin_amdgcn_s_barrier();                  // all: V reads done
        SFENCE();
        if (it + 1 < nch) {
            STAGE_V(gbase + (size_t)(it + 1) * CHUNK_BYTES);
            SFENCE();
            asm volatile("s_waitcnt vmcnt(6)" ::: "memory"); // own K(it+1) landed
            SFENCE();
        }
        __builtin_amdgcn_s_barrier();                  // all: K(it+1) ready
        SFENCE();                                      // block next K-read hoist
    }
#undef STAGE_K
#undef STAGE_V

    float lt = lacc + __shfl_xor(lacc, 32);
    int slab = sp * 2 + n;
    unsigned short* Yb = Y + ((((size_t)slab << 14) + q0 + l32) * 160);
    #pragma unroll
    for (int vt = 0; vt < 5; ++vt)
        #pragma unroll
        for (int g = 0; g < 4; ++g) {
            int vd = vt * 32 + 8 * g + 4 * half;
            uint2 w;
            w.x = pkfast(O[vt][4 * g], O[vt][4 * g + 1]);
            w.y = pkfast(O[vt][4 * g + 2], O[vt][4 * g + 3]);
            *(uint2*)(Yb + vd) = w;
        }
    if (lane < 32) L[(((size_t)slab) << 14) + q0 + lane] = lt;
}

// ---------------------------------------------------------------------------
// final conv + split combine + normalize
// ---------------------------------------------------------------------------
__launch_bounds__(256)
__global__ void k_convf(const unsigned short* __restrict__ Y, const float* __restrict__ L,
                        const unsigned short* __restrict__ Wp, const float* __restrict__ Wb,
                        float* __restrict__ out) {
    int tid = threadIdx.x, wid = tid >> 6, lane = tid & 63, quad = lane >> 4, l16 = lane & 15;
    int n = blockIdx.y;
    int p0 = blockIdx.x * 64;
    floatx4 acc[4][4];
    #pragma unroll
    for (int i = 0; i < 4; ++i)
        #pragma unroll
        for (int j = 0; j < 4; ++j) acc[i][j] = (floatx4)0.f;
    for (int kc = 0; kc < 5; ++kc) {
        int cb = kc * 32 + quad * 8;
        short8 a[4];
        #pragma unroll
        for (int mt = 0; mt < 4; ++mt)
            a[mt] = *(const short8*)(Wp + (size_t)(wid * 64 + mt * 16 + l16) * 160 + cb);
        #pragma unroll
        for (int sp = 0; sp < SPLITS; ++sp) {
            const unsigned short* Yb = Y + ((((size_t)(sp * 2 + n)) << 14) + p0) * 160;
            #pragma unroll
            for (int nt = 0; nt < 4; ++nt) {
                short8 b = *(const short8*)(Yb + (size_t)(nt * 16 + l16) * 160 + cb);
                #pragma unroll
                for (int mt = 0; mt < 4; ++mt) acc[mt][nt] = MFMA16(a[mt], b, acc[mt][nt]);
            }
        }
    }
    float linv[4];
    #pragma unroll
    for (int nt = 0; nt < 4; ++nt) {
        int p = p0 + nt * 16 + l16;
        float ls = 0.f;
        #pragma unroll
        for (int sp = 0; sp < SPLITS; ++sp) ls += L[(((size_t)(sp * 2 + n)) << 14) + p];
        linv[nt] = 1.f / ls;
    }
    #pragma unroll
    for (int mt = 0; mt < 4; ++mt)
        #pragma unroll
        for (int r = 0; r < 4; ++r) {
            int oc = wid * 64 + mt * 16 + quad * 4 + r;
            float bb = Wb[oc];
            float* orow = out + ((((size_t)n << 8) + oc) << 14) + p0;
            #pragma unroll
            for (int nt = 0; nt < 4; ++nt)
                orow[nt * 16 + l16] = acc[mt][nt][r] * linv[nt] + bb;
        }
}

// ---------------------------------------------------------------------------
extern "C" void kernel_launch(void* const* d_in, const int* in_sizes, int n_in,
                              void* d_out, int out_size, void* d_ws, size_t ws_size,
                              hipStream_t stream) {
    (void)in_sizes; (void)n_in; (void)out_size; (void)ws_size;
    const float* x   = (const float*)d_in[0];
    const float* thw = (const float*)d_in[1];
    const float* thb = (const float*)d_in[2];
    const float* phw = (const float*)d_in[3];
    const float* phb = (const float*)d_in[4];
    const float* gw_ = (const float*)d_in[5];
    const float* gb_ = (const float*)d_in[6];
    const float* Ww  = (const float*)d_in[7];
    const float* Wb  = (const float*)d_in[8];
    float* out = (float*)d_out;

    char* ws = (char*)d_ws;
    size_t off = 0;
    auto alloc = [&](size_t b) { size_t o = off; off += (b + 255) & ~(size_t)255; return o; };
    unsigned short* TW = (unsigned short*)(ws + alloc(32768 * 2));
    unsigned short* PW = (unsigned short*)(ws + alloc(32768 * 2));
    unsigned short* GW = (unsigned short*)(ws + alloc(32768 * 2));
    unsigned short* Wp = (unsigned short*)(ws + alloc(40960 * 2));
    unsigned short* Qb = (unsigned short*)(ws + alloc((size_t)32768 * 128 * 2));
    unsigned short* St = (unsigned short*)(ws + alloc((size_t)2 * 64 * CHUNK_BYTES));
    float*          Lb = (float*)(ws + alloc((size_t)SPLITS * 2 * 16384 * 4));
    // Y: [split*2+n][p][160]. xT (16.78 MB) + xpT (4.19 MB) alias into Y's
    // region: SPLITS=3 -> ybytes = 31.46 MB >= xT+xpT (20.97 MB). Both are
    // dead before attn writes Y (same-stream ordering), convf reads Y last.
    size_t ybytes = (size_t)SPLITS * 2 * 16384 * 160 * 2;
    unsigned short* Yb  = (unsigned short*)(ws + alloc(ybytes));
    unsigned short* xT  = Yb;
    unsigned short* xpT = (unsigned short*)((char*)Yb + (size_t)2 * 16384 * 256 * 2);

    k_prep<<<(139264 + 255) / 256, 256, 0, stream>>>(thw, phw, gw_, Ww, TW, PW, GW, Wp);
    k_xt<<<dim3(2048, 2), 256, 0, stream>>>(x, xT);
    k_poolT<<<dim3(1024, 2), 256, 0, stream>>>(x, xpT);
    k_convq<<<dim3(256, 2), 256, 0, stream>>>(xT, TW, thb, Qb);
    k_convkv<<<dim3(128, 2), 256, 0, stream>>>(xpT, PW, phb, GW, gb_, St);
    k_attn<<<dim3(128, 2, SPLITS), 256, 0, stream>>>(Qb, (const unsigned char*)St, Yb, Lb);
    k_convf<<<dim3(256, 2), 256, 0, stream>>>(Yb, Lb, Wp, Wb, out);
}